// Round 1
// baseline (1090.017 us; speedup 1.0000x reference)
//
#include <hip/hip_runtime.h>
#include <hip/hip_bf16.h>

#define NROWS 524288
#define DIM 256
#define NSEG 8192
#define SPB 8            // segments per block in gemm_pool_kernel
#define SEGS3 16         // segments per block in proj_kernel

typedef __attribute__((ext_vector_type(8))) short bf16x8;
typedef __attribute__((ext_vector_type(4))) float f32x4;

__device__ __forceinline__ short f2bf(float f) {
  union { float f; unsigned u; } a; a.f = f;
  unsigned r = a.u + 0x7fffu + ((a.u >> 16) & 1u);   // RNE
  return (short)(r >> 16);
}

// K1: seg_start[s] = lower_bound(batch_index, s), s in [0, NSEG]
__global__ void seg_start_kernel(const int* __restrict__ bi, int* __restrict__ ss) {
  int s = blockIdx.x * blockDim.x + threadIdx.x;
  if (s > NSEG) return;
  int lo = 0, hi = NROWS;
  while (lo < hi) { int mid = (lo + hi) >> 1; if (bi[mid] < s) lo = mid + 1; else hi = mid; }
  ss[s] = lo;
}

// K2: fused h = x@W1^T (bf16 MFMA) + segmented mean/max, bias at flush.
// Block owns segments [blk*SPB, blk*SPB+SPB) -> contiguous row range, no atomics.
__global__ __launch_bounds__(256, 2) void gemm_pool_kernel(
    const float* __restrict__ x, const int* __restrict__ bi,
    const float* __restrict__ W1, const float* __restrict__ b1,
    const int* __restrict__ ss, float* __restrict__ xpool) {
  __shared__ short x_lds[16 * 264];   // 16 rows x 256 k, bf16, padded stride
  __shared__ float hT[256 * 20];      // h transposed: [col][row], padded stride

  const int tid = threadIdx.x;
  const int wave = tid >> 6, lane = tid & 63;
  const int quad = lane >> 4, l16 = lane & 15;

  // W1 B-fragment register cache: this wave's 64 output cols, all K=256.
  // B frag layout: n = lane&15 (output col), k = quad*8 + j  (m89/m91-verified family)
  bf16x8 bfr[4][8];
  #pragma unroll
  for (int tt = 0; tt < 4; ++tt) {
    const int col = wave * 64 + tt * 16 + l16;
    #pragma unroll
    for (int ks = 0; ks < 8; ++ks) {
      const float* p = W1 + col * DIM + ks * 32 + quad * 8;
      f32x4 w0 = *(const f32x4*)p;
      f32x4 w1 = *(const f32x4*)(p + 4);
      bf16x8 f;
      f[0]=f2bf(w0[0]); f[1]=f2bf(w0[1]); f[2]=f2bf(w0[2]); f[3]=f2bf(w0[3]);
      f[4]=f2bf(w1[0]); f[5]=f2bf(w1[1]); f[6]=f2bf(w1[2]); f[7]=f2bf(w1[3]);
      bfr[tt][ks] = f;
    }
  }
  const float b1v = b1[tid];
  const int r0 = ss[blockIdx.x * SPB];
  const int r1 = ss[blockIdx.x * SPB + SPB];
  if (r0 >= r1) return;   // all 8 segments empty (block-uniform)

  int cur = bi[r0];
  float run_sum = 0.f, run_max = -3.0e38f;
  const int srow = tid >> 4;
  const int scol = (tid & 15) * 16;

  for (int base = r0; base < r1; base += 16) {
    int nr = r1 - base; if (nr > 16) nr = 16;
    // stage x chunk -> LDS bf16 (rows >= nr stay stale; their h rows are skipped)
    if (srow < nr) {
      const float* xp = x + (size_t)(base + srow) * DIM + scol;
      f32x4 v0 = *(const f32x4*)xp;
      f32x4 v1 = *(const f32x4*)(xp + 4);
      f32x4 v2 = *(const f32x4*)(xp + 8);
      f32x4 v3 = *(const f32x4*)(xp + 12);
      bf16x8 s0, s1;
      s0[0]=f2bf(v0[0]); s0[1]=f2bf(v0[1]); s0[2]=f2bf(v0[2]); s0[3]=f2bf(v0[3]);
      s0[4]=f2bf(v1[0]); s0[5]=f2bf(v1[1]); s0[6]=f2bf(v1[2]); s0[7]=f2bf(v1[3]);
      s1[0]=f2bf(v2[0]); s1[1]=f2bf(v2[1]); s1[2]=f2bf(v2[2]); s1[3]=f2bf(v2[3]);
      s1[4]=f2bf(v3[0]); s1[5]=f2bf(v3[1]); s1[6]=f2bf(v3[2]); s1[7]=f2bf(v3[3]);
      *(bf16x8*)&x_lds[srow * 264 + scol] = s0;
      *(bf16x8*)&x_lds[srow * 264 + scol + 8] = s1;
    }
    __syncthreads();
    // A frags: m = lane&15 (row), k = ks*32 + quad*8 + j
    bf16x8 af[8];
    #pragma unroll
    for (int ks = 0; ks < 8; ++ks)
      af[ks] = *(const bf16x8*)&x_lds[l16 * 264 + ks * 32 + quad * 8];
    f32x4 acc[4];
    #pragma unroll
    for (int tt = 0; tt < 4; ++tt) {
      f32x4 a = {0.f, 0.f, 0.f, 0.f};
      #pragma unroll
      for (int ks = 0; ks < 8; ++ks)
        a = __builtin_amdgcn_mfma_f32_16x16x32_bf16(af[ks], bfr[tt][ks], a, 0, 0, 0);
      acc[tt] = a;
    }
    // C layout: col = lane&15, rows = quad*4 + reg -> 4 contiguous rows: b128 store
    #pragma unroll
    for (int tt = 0; tt < 4; ++tt) {
      const int col = wave * 64 + tt * 16 + l16;
      *(f32x4*)&hT[col * 20 + quad * 4] = acc[tt];
    }
    __syncthreads();
    // segmented reduce: thread t owns column t
    f32x4 h0 = *(const f32x4*)&hT[tid * 20 + 0];
    f32x4 h1 = *(const f32x4*)&hT[tid * 20 + 4];
    f32x4 h2 = *(const f32x4*)&hT[tid * 20 + 8];
    f32x4 h3 = *(const f32x4*)&hT[tid * 20 + 12];
    float hv[16] = {h0[0],h0[1],h0[2],h0[3], h1[0],h1[1],h1[2],h1[3],
                    h2[0],h2[1],h2[2],h2[3], h3[0],h3[1],h3[2],h3[3]};
    #pragma unroll
    for (int r = 0; r < 16; ++r) {
      if (r < nr) {
        int s = bi[base + r];            // block-uniform
        if (s != cur) {                  // uniform branch: flush completed segment
          int cnt = ss[cur + 1] - ss[cur];
          xpool[(size_t)cur * 512 + tid]       = run_sum / (float)cnt + b1v;
          xpool[(size_t)cur * 512 + 256 + tid] = run_max + b1v;
          cur = s; run_sum = 0.f; run_max = -3.0e38f;
        }
        run_sum += hv[r];
        run_max = fmaxf(run_max, hv[r]);
      }
    }
  }
  // final flush
  {
    int cnt = ss[cur + 1] - ss[cur];
    xpool[(size_t)cur * 512 + tid]       = run_sum / (float)cnt + b1v;
    xpool[(size_t)cur * 512 + 256 + tid] = run_max + b1v;
  }
}

// K3: out_pool[s][j] = sum_k xpool[s][k] * Wp[j][k] + bp[j]   (2.1 GFLOP, VALU)
__global__ __launch_bounds__(256) void proj_kernel(
    const float* __restrict__ xpool, const float* __restrict__ Wp,
    const float* __restrict__ bp, float* __restrict__ out_pool) {
  __shared__ float xp_lds[SEGS3 * 512];
  const int tid = threadIdx.x;
  const size_t s0 = (size_t)blockIdx.x * SEGS3;
  for (int i = tid; i < SEGS3 * 128; i += 256)
    *(f32x4*)&xp_lds[i * 4] = *(const f32x4*)&xpool[s0 * 512 + (size_t)i * 4];
  __syncthreads();
  float acc[SEGS3];
  #pragma unroll
  for (int s = 0; s < SEGS3; ++s) acc[s] = 0.f;
  for (int k0 = 0; k0 < 512; k0 += 4) {
    f32x4 wp = *(const f32x4*)&Wp[(size_t)tid * 512 + k0];
    #pragma unroll
    for (int s = 0; s < SEGS3; ++s) {
      f32x4 xv = *(const f32x4*)&xp_lds[s * 512 + k0];   // same-addr broadcast
      acc[s] += xv[0]*wp[0] + xv[1]*wp[1] + xv[2]*wp[2] + xv[3]*wp[3];
    }
  }
  const float b = bp[tid];
  #pragma unroll
  for (int s = 0; s < SEGS3; ++s)
    out_pool[(s0 + s) * 256 + tid] = acc[s] + b;
}

// K4: out[n][:] = out_pool[batch_index[n]][:]   (write-bound, float4)
__global__ void gather_kernel(const int* __restrict__ bi,
                              const float* __restrict__ out_pool,
                              float* __restrict__ out) {
  const size_t idx = (size_t)blockIdx.x * blockDim.x + threadIdx.x; // float4 units
  const int n  = (int)(idx >> 6);    // 64 float4 per row
  const int c4 = (int)(idx & 63);
  const int s = bi[n];
  f32x4 v = *(const f32x4*)&out_pool[(size_t)s * 256 + c4 * 4];
  *(f32x4*)&out[(size_t)n * 256 + (size_t)c4 * 4] = v;
}

extern "C" void kernel_launch(void* const* d_in, const int* in_sizes, int n_in,
                              void* d_out, int out_size, void* d_ws, size_t ws_size,
                              hipStream_t stream) {
  const float* x  = (const float*)d_in[0];
  const int*   bi = (const int*)d_in[1];
  const float* W1 = (const float*)d_in[2];
  const float* b1 = (const float*)d_in[3];
  const float* Wp = (const float*)d_in[4];
  const float* bp = (const float*)d_in[5];
  float* out = (float*)d_out;

  char* ws = (char*)d_ws;
  int*   ss       = (int*)ws;                                   // 8193 ints
  float* xpool    = (float*)(ws + 64 * 1024);                   // [8192][512] f32 = 16 MiB
  float* out_pool = (float*)(ws + 64 * 1024 + (size_t)NSEG * 512 * 4); // [8192][256] = 8 MiB

  seg_start_kernel<<<(NSEG + 256) / 256, 256, 0, stream>>>(bi, ss);
  gemm_pool_kernel<<<NSEG / SPB, 256, 0, stream>>>(x, bi, W1, b1, ss, xpool);
  proj_kernel<<<NSEG / SEGS3, 256, 0, stream>>>(xpool, Wp, bp, out_pool);
  gather_kernel<<<(size_t)NROWS * (DIM / 4) / 256, 256, 0, stream>>>(bi, out_pool, out);
}